// Round 4
// baseline (802.393 us; speedup 1.0000x reference)
//
#include <hip/hip_runtime.h>
#include <stdint.h>

#define HH 64      // hidden
#define II 32      // input features
#define TSTEPS 512
#define BATCH 1024
#define CH 64      // timesteps per LDS x-chunk
#define NCH (TSTEPS / CH)
#define WPB 4      // waves (batch elements) per block

typedef float f32x2 __attribute__((ext_vector_type(2)));
typedef float f32x4 __attribute__((ext_vector_type(4)));

// tanh(x) = 1 - 2/(exp(2x)+1); hw exp2 + hw rcp; saturates correctly at +/-inf
__device__ __forceinline__ float fast_tanh(float x) {
    float e = __builtin_amdgcn_exp2f(x * 2.885390081777927f); // 2*log2(e)
    return fmaf(-2.0f, __builtin_amdgcn_rcpf(e + 1.0f), 1.0f);
}

// stage 8KB (64 timesteps x 32 floats) global -> LDS, linear, 8x 16B/lane
__device__ __forceinline__ void stage8k(const float* g, float* l, int lane) {
#pragma unroll
    for (int k = 0; k < 8; ++k) {
        __builtin_amdgcn_global_load_lds(
            (const __attribute__((address_space(1))) void*)(g + k * 256 + lane * 4),
            (__attribute__((address_space(3))) void*)(l + k * 256),
            16, 0, 0);
    }
}

// load a row of N floats into f32x2 pairs via float4 loads
#define LOADW2(dst, src, N)                                                   \
    {                                                                         \
        const f32x4* p_ = (const f32x4*)(src);                                \
        _Pragma("unroll") for (int k_ = 0; k_ < (N) / 4; ++k_) {              \
            f32x4 v_ = p_[k_];                                                \
            dst[2 * k_] = v_.lo;                                              \
            dst[2 * k_ + 1] = v_.hi;                                          \
        }                                                                     \
    }

__global__ void __launch_bounds__(256, 1) rnn_fused(
    const float* __restrict__ x,     // [B,T,II]
    const float* __restrict__ Wih1,  // [H,II]
    const float* __restrict__ Whh1,  // [H,H]
    const float* __restrict__ bih1,
    const float* __restrict__ bhh1,
    const float* __restrict__ Wih2,  // [H,H]
    const float* __restrict__ Whh2,  // [H,H]
    const float* __restrict__ bih2,
    const float* __restrict__ bhh2,
    const float* __restrict__ Wfc1,  // [H,H]
    const float* __restrict__ bfc1,
    const float* __restrict__ Wfc2,  // [32,H]
    const float* __restrict__ bfc2,
    float* __restrict__ out)         // [B,32]
{
    const int wave = threadIdx.x >> 6;
    const int o = threadIdx.x & 63;             // lane == output component
    const int b = blockIdx.x * WPB + wave;      // batch element of this wave

    __shared__ __align__(16) float xs[WPB][2][CH * II];  // 4 x 2 x 8KB = 64KB
    __shared__ __align__(16) float hb1[WPB][HH];         // h1 broadcast buffer
    __shared__ __align__(16) float hb2[WPB][HH];         // h2 broadcast buffer

    // ---- weight rows into VGPRs as f32x2 pairs (224 regs, compile-time idx) ----
    f32x2 wih1[II / 2], whh1[HH / 2], wih2[HH / 2], whh2[HH / 2];
    LOADW2(wih1, Wih1 + o * II, II);
    LOADW2(whh1, Whh1 + o * HH, HH);
    LOADW2(wih2, Wih2 + o * HH, HH);
    LOADW2(whh2, Whh2 + o * HH, HH);
    const float b1 = bih1[o] + bhh1[o];
    const float b2 = bih2[o] + bhh2[o];

    hb2[wave][o] = 0.f;  // h2(-1) = 0 (read before first write)

    const float* xb = x + (size_t)b * TSTEPS * II;
    float* l0 = &xs[wave][0][0];
    float* l1 = &xs[wave][1][0];

    // prefetch chunk 0 and wait (per-wave vmcnt; waves are independent)
    stage8k(xb, l0, o);
    asm volatile("s_waitcnt vmcnt(0)" ::: "memory");

    float acc1p = b1;   // carries b1 + Whh1 @ h1(t-1)
    float h2v = 0.f;

#pragma unroll 1
    for (int c = 0; c < NCH; ++c) {
        const float* cur = (c & 1) ? l1 : l0;
        float* nxt = (c & 1) ? l0 : l1;
        if (c + 1 < NCH) stage8k(xb + (c + 1) * CH * II, nxt, o);

#pragma unroll 1
        for (int tt = 0; tt < CH; ++tt) {
            const float* xr = cur + tt * II;

            // ---- layer1 ih GEMV: wave-uniform x reads, packed FMA ----
            f32x2 a0 = {acc1p, 0.f}, a1 = {0.f, 0.f};
#pragma unroll
            for (int k = 0; k < II / 4; ++k) {
                f32x4 xq = *(const f32x4*)(xr + 4 * k);  // uniform broadcast
                a0 = __builtin_elementwise_fma(xq.lo, wih1[2 * k], a0);
                a1 = __builtin_elementwise_fma(xq.hi, wih1[2 * k + 1], a1);
            }
            float h1 = fast_tanh((a0.x + a1.x) + (a0.y + a1.y));
            hb1[wave][o] = h1;  // ds_write; latency covered by h2-round below

            // ---- Whh2 @ h2(t-1): hb2 written one full step ago (latency ok) ----
            f32x2 q0 = {b2, 0.f}, q1 = {0.f, 0.f};
#pragma unroll
            for (int k = 0; k < HH / 4; ++k) {
                f32x4 hq = *(const f32x4*)(&hb2[wave][4 * k]);  // uniform
                q0 = __builtin_elementwise_fma(hq.lo, whh2[2 * k], q0);
                q1 = __builtin_elementwise_fma(hq.hi, whh2[2 * k + 1], q1);
            }
            float acc2 = (q0.x + q1.x) + (q0.y + q1.y);

            // ---- h1 round: Wih2@h1 (layer2 now) + Whh1@h1 (next-step layer1) ----
            f32x2 c0 = {acc2, 0.f}, c1 = {0.f, 0.f};
            f32x2 p0 = {b1, 0.f}, p1 = {0.f, 0.f};
#pragma unroll
            for (int k = 0; k < HH / 4; ++k) {
                f32x4 hq = *(const f32x4*)(&hb1[wave][4 * k]);  // uniform
                c0 = __builtin_elementwise_fma(hq.lo, wih2[2 * k], c0);
                c1 = __builtin_elementwise_fma(hq.hi, wih2[2 * k + 1], c1);
                p0 = __builtin_elementwise_fma(hq.lo, whh1[2 * k], p0);
                p1 = __builtin_elementwise_fma(hq.hi, whh1[2 * k + 1], p1);
            }
            acc1p = (p0.x + p1.x) + (p0.y + p1.y);
            h2v = fast_tanh((c0.x + c1.x) + (c0.y + c1.y));
            hb2[wave][o] = h2v;  // ds_write; latency covered by next step's ih
        }

        // staging for chunk c+1 must have landed before we read it
        asm volatile("s_waitcnt vmcnt(0)" ::: "memory");
    }

    // ---- FC head (h2 final vector is in hb2[wave][*]) ----
    f32x2 wf[HH / 2];
    LOADW2(wf, Wfc1 + o * HH, HH);
    f32x2 z0 = {bfc1[o], 0.f}, z1 = {0.f, 0.f};
#pragma unroll
    for (int k = 0; k < HH / 4; ++k) {
        f32x4 hq = *(const f32x4*)(&hb2[wave][4 * k]);
        z0 = __builtin_elementwise_fma(hq.lo, wf[2 * k], z0);
        z1 = __builtin_elementwise_fma(hq.hi, wf[2 * k + 1], z1);
    }
    float z = fmaxf((z0.x + z1.x) + (z0.y + z1.y), 0.f);
    hb1[wave][o] = z;  // broadcast z through LDS

    const int oo = o & 31;  // lanes 32..63 duplicate rows 0..31 (not stored)
    LOADW2(wf, Wfc2 + oo * HH, HH);
    f32x2 y0 = {bfc2[oo], 0.f}, y1 = {0.f, 0.f};
#pragma unroll
    for (int k = 0; k < HH / 4; ++k) {
        f32x4 zq = *(const f32x4*)(&hb1[wave][4 * k]);
        y0 = __builtin_elementwise_fma(zq.lo, wf[2 * k], y0);
        y1 = __builtin_elementwise_fma(zq.hi, wf[2 * k + 1], y1);
    }
    if (o < 32) out[b * 32 + o] = (y0.x + y1.x) + (y0.y + y1.y);
}

extern "C" void kernel_launch(void* const* d_in, const int* in_sizes, int n_in,
                              void* d_out, int out_size, void* d_ws, size_t ws_size,
                              hipStream_t stream) {
    const float* x    = (const float*)d_in[0];
    const float* Wih1 = (const float*)d_in[1];
    const float* Whh1 = (const float*)d_in[2];
    const float* bih1 = (const float*)d_in[3];
    const float* bhh1 = (const float*)d_in[4];
    const float* Wih2 = (const float*)d_in[5];
    const float* Whh2 = (const float*)d_in[6];
    const float* bih2 = (const float*)d_in[7];
    const float* bhh2 = (const float*)d_in[8];
    const float* Wfc1 = (const float*)d_in[9];
    const float* bfc1 = (const float*)d_in[10];
    const float* Wfc2 = (const float*)d_in[11];
    const float* bfc2 = (const float*)d_in[12];
    float* out = (float*)d_out;

    hipLaunchKernelGGL(rnn_fused, dim3(BATCH / WPB), dim3(64 * WPB), 0, stream,
                       x, Wih1, Whh1, bih1, bhh1, Wih2, Whh2, bih2, bhh2,
                       Wfc1, bfc1, Wfc2, bfc2, out);
}

// Round 5
// 546.918 us; speedup vs baseline: 1.4671x; 1.4671x over previous
//
#include <hip/hip_runtime.h>
#include <stdint.h>

#define HH 64      // hidden
#define II 32      // input features
#define TSTEPS 512
#define BATCH 1024
#define WPB 4      // waves (batch elements) per block in phase 2
#define CH2 32     // timesteps per LDS xw-chunk (32*64 floats = 8KB)
#define NCH2 (TSTEPS / CH2)
#define XWBYTES ((size_t)BATCH * TSTEPS * HH * 4)

typedef float f32x2 __attribute__((ext_vector_type(2)));
typedef float f32x4 __attribute__((ext_vector_type(4)));

// tanh(x) = 1 - 2/(exp(2x)+1); hw exp2 + hw rcp; saturates correctly at +/-inf
__device__ __forceinline__ float fast_tanh(float x) {
    float e = __builtin_amdgcn_exp2f(x * 2.885390081777927f); // 2*log2(e)
    return fmaf(-2.0f, __builtin_amdgcn_rcpf(e + 1.0f), 1.0f);
}

// stage 8KB global -> LDS, linear, 8x 16B/lane
__device__ __forceinline__ void stage8k(const float* g, float* l, int lane) {
#pragma unroll
    for (int k = 0; k < 8; ++k) {
        __builtin_amdgcn_global_load_lds(
            (const __attribute__((address_space(1))) void*)(g + k * 256 + lane * 4),
            (__attribute__((address_space(3))) void*)(l + k * 256),
            16, 0, 0);
    }
}

// load a row of N floats into f32x2 pairs via float4 loads
#define LOADW2(dst, src, N)                                                   \
    {                                                                         \
        const f32x4* p_ = (const f32x4*)(src);                                \
        _Pragma("unroll") for (int k_ = 0; k_ < (N) / 4; ++k_) {              \
            f32x4 v_ = p_[k_];                                                \
            dst[2 * k_] = v_.lo;                                              \
            dst[2 * k_ + 1] = v_.hi;                                          \
        }                                                                     \
    }

// opaque identity on each weight register: forbids rematerialization-by-reload
#define KEEPALIVE2(arr, n)                                                    \
    {                                                                         \
        _Pragma("unroll") for (int k_ = 0; k_ < (n); ++k_) {                  \
            float t0_ = arr[k_].x, t1_ = arr[k_].y;                           \
            asm volatile("" : "+v"(t0_), "+v"(t1_));                          \
            arr[k_].x = t0_; arr[k_].y = t1_;                                 \
        }                                                                     \
    }

// ---------------- Phase 1: xw[b,t,o] = x[b,t,:]@Wih1[o,:] + bih1[o]+bhh1[o]
__global__ void __launch_bounds__(256) xw_precompute(
    const float* __restrict__ x,     // [B,T,II]
    const float* __restrict__ Wih1,  // [H,II]
    const float* __restrict__ bih1,
    const float* __restrict__ bhh1,
    float* __restrict__ xw)          // [B*T, H]
{
    const int o = threadIdx.x & 63;
    const int w = (blockIdx.x << 2) | (threadIdx.x >> 6);  // wave id, 0..8191

    f32x2 wih[II / 2];
    LOADW2(wih, Wih1 + o * II, II);
    const float bb = bih1[o] + bhh1[o];

    const int R = BATCH * TSTEPS;           // 524288 rows
#pragma unroll 1
    for (int r = w; r < R; r += 8192) {     // 64 rows per wave
        const f32x4* xr = (const f32x4*)(x + (size_t)r * II);  // wave-uniform
        f32x2 a0 = {bb, 0.f}, a1 = {0.f, 0.f};
#pragma unroll
        for (int k = 0; k < II / 4; ++k) {
            f32x4 q = xr[k];
            a0 = __builtin_elementwise_fma(q.lo, wih[2 * k], a0);
            a1 = __builtin_elementwise_fma(q.hi, wih[2 * k + 1], a1);
        }
        xw[(size_t)r * HH + o] = (a0.x + a1.x) + (a0.y + a1.y);
    }
}

// ---------------- Phase 2: recurrence (xw streamed, 192 resident weights)
__global__ void __launch_bounds__(256, 1) rnn_rec(
    const float* __restrict__ xw,    // [B,T,H] precomputed
    const float* __restrict__ Whh1,  // [H,H]
    const float* __restrict__ Wih2,  // [H,H]
    const float* __restrict__ Whh2,  // [H,H]
    const float* __restrict__ bih2,
    const float* __restrict__ bhh2,
    const float* __restrict__ Wfc1,  // [H,H]
    const float* __restrict__ bfc1,
    const float* __restrict__ Wfc2,  // [32,H]
    const float* __restrict__ bfc2,
    float* __restrict__ out)         // [B,32]
{
    const int wave = threadIdx.x >> 6;
    const int o = threadIdx.x & 63;             // lane == output component
    const int b = blockIdx.x * WPB + wave;      // batch element of this wave

    __shared__ __align__(16) float xs[WPB][2][CH2 * HH];  // 4 x 2 x 8KB = 64KB
    __shared__ __align__(16) float hb1[WPB][HH];          // h1 broadcast buffer
    __shared__ __align__(16) float hb2[WPB][HH];          // h2 broadcast buffer

    // ---- 192 weight floats resident in VGPRs; remat forbidden ----
    f32x2 whh1[HH / 2], wih2[HH / 2], whh2[HH / 2];
    LOADW2(whh1, Whh1 + o * HH, HH);
    LOADW2(wih2, Wih2 + o * HH, HH);
    LOADW2(whh2, Whh2 + o * HH, HH);
    KEEPALIVE2(whh1, HH / 2);
    KEEPALIVE2(wih2, HH / 2);
    KEEPALIVE2(whh2, HH / 2);
    const float b2 = bih2[o] + bhh2[o];

    hb2[wave][o] = 0.f;  // h2(-1) = 0 (read before first write)

    const float* xwb = xw + (size_t)b * TSTEPS * HH;
    float* l0 = &xs[wave][0][0];
    float* l1 = &xs[wave][1][0];

    // prefetch chunk 0 and wait (per-wave vmcnt; waves are independent)
    stage8k(xwb, l0, o);
    asm volatile("s_waitcnt vmcnt(0)" ::: "memory");

    float acc1p = 0.f;   // carries Whh1 @ h1(t-1)  (biases live inside xw)
    float h2v = 0.f;

#pragma unroll 1
    for (int c = 0; c < NCH2; ++c) {
        const float* cur = (c & 1) ? l1 : l0;
        float* nxt = (c & 1) ? l0 : l1;
        if (c + 1 < NCH2) stage8k(xwb + (c + 1) * CH2 * HH, nxt, o);

        float xwcur = cur[o];  // xw for step 0 of this chunk (per-lane read)
#pragma unroll 1
        for (int tt = 0; tt < CH2; ++tt) {
            // prefetch next step's xw (wraps harmlessly at chunk tail)
            float xwnxt = cur[(((tt + 1) & (CH2 - 1)) * HH) + o];

            // ---- layer1: pre-activation = xw_t (has bias) + Whh1@h1(t-1) ----
            float h1 = fast_tanh(xwcur + acc1p);
            hb1[wave][o] = h1;  // ds_write; latency covered by whh2 round below

            // ---- Whh2 @ h2(t-1): hb2 written one full step ago ----
            f32x2 q0 = {b2, 0.f}, q1 = {0.f, 0.f};
#pragma unroll
            for (int k = 0; k < HH / 4; ++k) {
                f32x4 hq = *(const f32x4*)(&hb2[wave][4 * k]);  // uniform
                q0 = __builtin_elementwise_fma(hq.lo, whh2[2 * k], q0);
                q1 = __builtin_elementwise_fma(hq.hi, whh2[2 * k + 1], q1);
            }
            float acc2 = (q0.x + q1.x) + (q0.y + q1.y);

            // ---- h1 round: Wih2@h1 (layer2 now) + Whh1@h1 (next-step rec) ----
            f32x2 c0 = {acc2, 0.f}, c1 = {0.f, 0.f};
            f32x2 p0 = {0.f, 0.f}, p1 = {0.f, 0.f};
#pragma unroll
            for (int k = 0; k < HH / 4; ++k) {
                f32x4 hq = *(const f32x4*)(&hb1[wave][4 * k]);  // uniform
                c0 = __builtin_elementwise_fma(hq.lo, wih2[2 * k], c0);
                c1 = __builtin_elementwise_fma(hq.hi, wih2[2 * k + 1], c1);
                p0 = __builtin_elementwise_fma(hq.lo, whh1[2 * k], p0);
                p1 = __builtin_elementwise_fma(hq.hi, whh1[2 * k + 1], p1);
            }
            acc1p = (p0.x + p1.x) + (p0.y + p1.y);
            h2v = fast_tanh((c0.x + c1.x) + (c0.y + c1.y));
            hb2[wave][o] = h2v;  // consumed next step (latency covered)
            xwcur = xwnxt;
        }

        // staging for chunk c+1 must have landed before we read it
        asm volatile("s_waitcnt vmcnt(0)" ::: "memory");
        xwcur = 0.f;  // (dead; reloaded at chunk start)
    }

    // ---- FC head (final h2 vector is in hb2[wave][*]) ----
    f32x2 wf[HH / 2];
    LOADW2(wf, Wfc1 + o * HH, HH);
    f32x2 z0 = {bfc1[o], 0.f}, z1 = {0.f, 0.f};
#pragma unroll
    for (int k = 0; k < HH / 4; ++k) {
        f32x4 hq = *(const f32x4*)(&hb2[wave][4 * k]);
        z0 = __builtin_elementwise_fma(hq.lo, wf[2 * k], z0);
        z1 = __builtin_elementwise_fma(hq.hi, wf[2 * k + 1], z1);
    }
    float z = fmaxf((z0.x + z1.x) + (z0.y + z1.y), 0.f);
    hb1[wave][o] = z;  // broadcast z through LDS

    const int oo = o & 31;  // lanes 32..63 duplicate rows 0..31 (not stored)
    LOADW2(wf, Wfc2 + oo * HH, HH);
    f32x2 y0 = {bfc2[oo], 0.f}, y1 = {0.f, 0.f};
#pragma unroll
    for (int k = 0; k < HH / 4; ++k) {
        f32x4 zq = *(const f32x4*)(&hb1[wave][4 * k]);
        y0 = __builtin_elementwise_fma(zq.lo, wf[2 * k], y0);
        y1 = __builtin_elementwise_fma(zq.hi, wf[2 * k + 1], y1);
    }
    if (o < 32) out[b * 32 + o] = (y0.x + y1.x) + (y0.y + y1.y);
}

// ---------------- Fallback (round-4 kernel, used only if ws too small) ----
__global__ void __launch_bounds__(256, 1) rnn_fused_fb(
    const float* __restrict__ x, const float* __restrict__ Wih1,
    const float* __restrict__ Whh1, const float* __restrict__ bih1,
    const float* __restrict__ bhh1, const float* __restrict__ Wih2,
    const float* __restrict__ Whh2, const float* __restrict__ bih2,
    const float* __restrict__ bhh2, const float* __restrict__ Wfc1,
    const float* __restrict__ bfc1, const float* __restrict__ Wfc2,
    const float* __restrict__ bfc2, float* __restrict__ out)
{
    const int wave = threadIdx.x >> 6;
    const int o = threadIdx.x & 63;
    const int b = blockIdx.x * WPB + wave;

    __shared__ __align__(16) float xs[WPB][2][64 * II];
    __shared__ __align__(16) float hb1[WPB][HH];
    __shared__ __align__(16) float hb2[WPB][HH];

    f32x2 wih1[II / 2], whh1[HH / 2], wih2[HH / 2], whh2[HH / 2];
    LOADW2(wih1, Wih1 + o * II, II);
    LOADW2(whh1, Whh1 + o * HH, HH);
    LOADW2(wih2, Wih2 + o * HH, HH);
    LOADW2(whh2, Whh2 + o * HH, HH);
    const float b1 = bih1[o] + bhh1[o];
    const float b2 = bih2[o] + bhh2[o];
    hb2[wave][o] = 0.f;

    const float* xb = x + (size_t)b * TSTEPS * II;
    float* l0 = &xs[wave][0][0];
    float* l1 = &xs[wave][1][0];
    stage8k(xb, l0, o);
    asm volatile("s_waitcnt vmcnt(0)" ::: "memory");

    float acc1p = b1;
    float h2v = 0.f;
#pragma unroll 1
    for (int c = 0; c < TSTEPS / 64; ++c) {
        const float* cur = (c & 1) ? l1 : l0;
        float* nxt = (c & 1) ? l0 : l1;
        if (c + 1 < TSTEPS / 64) stage8k(xb + (c + 1) * 64 * II, nxt, o);
#pragma unroll 1
        for (int tt = 0; tt < 64; ++tt) {
            const float* xr = cur + tt * II;
            f32x2 a0 = {acc1p, 0.f}, a1 = {0.f, 0.f};
#pragma unroll
            for (int k = 0; k < II / 4; ++k) {
                f32x4 xq = *(const f32x4*)(xr + 4 * k);
                a0 = __builtin_elementwise_fma(xq.lo, wih1[2 * k], a0);
                a1 = __builtin_elementwise_fma(xq.hi, wih1[2 * k + 1], a1);
            }
            float h1 = fast_tanh((a0.x + a1.x) + (a0.y + a1.y));
            hb1[wave][o] = h1;
            f32x2 q0 = {b2, 0.f}, q1 = {0.f, 0.f};
#pragma unroll
            for (int k = 0; k < HH / 4; ++k) {
                f32x4 hq = *(const f32x4*)(&hb2[wave][4 * k]);
                q0 = __builtin_elementwise_fma(hq.lo, whh2[2 * k], q0);
                q1 = __builtin_elementwise_fma(hq.hi, whh2[2 * k + 1], q1);
            }
            float acc2 = (q0.x + q1.x) + (q0.y + q1.y);
            f32x2 c0 = {acc2, 0.f}, c1 = {0.f, 0.f};
            f32x2 p0 = {b1, 0.f}, p1 = {0.f, 0.f};
#pragma unroll
            for (int k = 0; k < HH / 4; ++k) {
                f32x4 hq = *(const f32x4*)(&hb1[wave][4 * k]);
                c0 = __builtin_elementwise_fma(hq.lo, wih2[2 * k], c0);
                c1 = __builtin_elementwise_fma(hq.hi, wih2[2 * k + 1], c1);
                p0 = __builtin_elementwise_fma(hq.lo, whh1[2 * k], p0);
                p1 = __builtin_elementwise_fma(hq.hi, whh1[2 * k + 1], p1);
            }
            acc1p = (p0.x + p1.x) + (p0.y + p1.y);
            h2v = fast_tanh((c0.x + c1.x) + (c0.y + c1.y));
            hb2[wave][o] = h2v;
        }
        asm volatile("s_waitcnt vmcnt(0)" ::: "memory");
    }

    f32x2 wf[HH / 2];
    LOADW2(wf, Wfc1 + o * HH, HH);
    f32x2 z0 = {bfc1[o], 0.f}, z1 = {0.f, 0.f};
#pragma unroll
    for (int k = 0; k < HH / 4; ++k) {
        f32x4 hq = *(const f32x4*)(&hb2[wave][4 * k]);
        z0 = __builtin_elementwise_fma(hq.lo, wf[2 * k], z0);
        z1 = __builtin_elementwise_fma(hq.hi, wf[2 * k + 1], z1);
    }
    float z = fmaxf((z0.x + z1.x) + (z0.y + z1.y), 0.f);
    hb1[wave][o] = z;
    const int oo = o & 31;
    LOADW2(wf, Wfc2 + oo * HH, HH);
    f32x2 y0 = {bfc2[oo], 0.f}, y1 = {0.f, 0.f};
#pragma unroll
    for (int k = 0; k < HH / 4; ++k) {
        f32x4 zq = *(const f32x4*)(&hb1[wave][4 * k]);
        y0 = __builtin_elementwise_fma(zq.lo, wf[2 * k], y0);
        y1 = __builtin_elementwise_fma(zq.hi, wf[2 * k + 1], y1);
    }
    if (o < 32) out[b * 32 + o] = (y0.x + y1.x) + (y0.y + y1.y);
}

extern "C" void kernel_launch(void* const* d_in, const int* in_sizes, int n_in,
                              void* d_out, int out_size, void* d_ws, size_t ws_size,
                              hipStream_t stream) {
    const float* x    = (const float*)d_in[0];
    const float* Wih1 = (const float*)d_in[1];
    const float* Whh1 = (const float*)d_in[2];
    const float* bih1 = (const float*)d_in[3];
    const float* bhh1 = (const float*)d_in[4];
    const float* Wih2 = (const float*)d_in[5];
    const float* Whh2 = (const float*)d_in[6];
    const float* bih2 = (const float*)d_in[7];
    const float* bhh2 = (const float*)d_in[8];
    const float* Wfc1 = (const float*)d_in[9];
    const float* bfc1 = (const float*)d_in[10];
    const float* Wfc2 = (const float*)d_in[11];
    const float* bfc2 = (const float*)d_in[12];
    float* out = (float*)d_out;

    if (ws_size >= XWBYTES) {
        float* xw = (float*)d_ws;
        hipLaunchKernelGGL(xw_precompute, dim3(2048), dim3(256), 0, stream,
                           x, Wih1, bih1, bhh1, xw);
        hipLaunchKernelGGL(rnn_rec, dim3(BATCH / WPB), dim3(64 * WPB), 0, stream,
                           xw, Whh1, Wih2, Whh2, bih2, bhh2,
                           Wfc1, bfc1, Wfc2, bfc2, out);
    } else {
        hipLaunchKernelGGL(rnn_fused_fb, dim3(BATCH / WPB), dim3(64 * WPB), 0, stream,
                           x, Wih1, Whh1, bih1, bhh1, Wih2, Whh2, bih2, bhh2,
                           Wfc1, bfc1, Wfc2, bfc2, out);
    }
}

// Round 6
// 462.075 us; speedup vs baseline: 1.7365x; 1.1836x over previous
//
#include <hip/hip_runtime.h>
#include <stdint.h>

#define HH 64      // hidden
#define II 32      // input features
#define TSTEPS 512
#define BATCH 1024
#define CH2 32     // timesteps per LDS xw-chunk (32*64 floats = 8KB)
#define NCH2 (TSTEPS / CH2)
#define XWBYTES ((size_t)BATCH * TSTEPS * HH * 4)

typedef float f32x2 __attribute__((ext_vector_type(2)));
typedef float f32x4 __attribute__((ext_vector_type(4)));

// tanh(x) = 1 - 2/(exp(2x)+1); hw exp2 + hw rcp; saturates correctly at +/-inf
__device__ __forceinline__ float fast_tanh(float x) {
    float e = __builtin_amdgcn_exp2f(x * 2.885390081777927f); // 2*log2(e)
    return fmaf(-2.0f, __builtin_amdgcn_rcpf(e + 1.0f), 1.0f);
}

// load a row of N floats into f32x2 pairs via float4 loads
#define LOADW2(dst, src, N)                                                   \
    {                                                                         \
        const f32x4* p_ = (const f32x4*)(src);                                \
        _Pragma("unroll") for (int k_ = 0; k_ < (N) / 4; ++k_) {              \
            f32x4 v_ = p_[k_];                                                \
            dst[2 * k_] = v_.lo;                                              \
            dst[2 * k_ + 1] = v_.hi;                                          \
        }                                                                     \
    }

// ---------------- Phase 1: xw[b,t,o] = x[b,t,:]@Wih1[o,:] + bih1[o]+bhh1[o]
// 64 rows per block, LDS-staged coalesced, wave-uniform reads, full unroll.
__global__ void __launch_bounds__(256) xw_precompute(
    const float* __restrict__ x,     // [B*T, II]
    const float* __restrict__ Wih1,  // [H,II]
    const float* __restrict__ bih1,
    const float* __restrict__ bhh1,
    float* __restrict__ xw)          // [B*T, H]
{
    const int tid = threadIdx.x;
    const int w = tid >> 6;
    const int l = tid & 63;
    const int rbase = blockIdx.x * 64;

    __shared__ __align__(16) float xsm[64 * II];  // 8 KB

    const float* gx = x + (size_t)rbase * II;
#pragma unroll
    for (int k = 0; k < 2; ++k) {
        const int off = w * 512 + k * 256;
        __builtin_amdgcn_global_load_lds(
            (const __attribute__((address_space(1))) void*)(gx + off + l * 4),
            (__attribute__((address_space(3))) void*)(xsm + off),
            16, 0, 0);
    }
    asm volatile("s_waitcnt vmcnt(0)" ::: "memory");
    __syncthreads();

    f32x2 wv[II / 2];
    LOADW2(wv, Wih1 + l * II, II);     // lane l owns output row l
    const float bb = bih1[l] + bhh1[l];
    float* outb = xw + (size_t)rbase * HH;

#pragma unroll
    for (int i = 0; i < 16; ++i) {
        const int r = w + i * 4;       // wave-uniform row index
        const float* xr = xsm + r * II;
        f32x2 a0 = {bb, 0.f}, a1 = {0.f, 0.f};
#pragma unroll
        for (int k = 0; k < II / 4; ++k) {
            f32x4 q = *(const f32x4*)(xr + 4 * k);  // uniform LDS broadcast
            a0 = __builtin_elementwise_fma(q.lo, wv[2 * k], a0);
            a1 = __builtin_elementwise_fma(q.hi, wv[2 * k + 1], a1);
        }
        outb[r * HH + l] = (a0.x + a1.x) + (a0.y + a1.y);  // coalesced
    }
}

// ---------------- Phase 2: recurrence, split-K, 2 waves/block, 1 batch/block
// lane l: output o = w*32+(l&31), K-half kh = l>>5. 96 weight floats/lane.
__global__ void __launch_bounds__(128, 2) rnn_rec(
    const float* __restrict__ xw,    // [B,T,H] precomputed (bias folded)
    const float* __restrict__ Whh1,  // [H,H]
    const float* __restrict__ Wih2,  // [H,H]
    const float* __restrict__ Whh2,  // [H,H]
    const float* __restrict__ bih2,
    const float* __restrict__ bhh2,
    const float* __restrict__ Wfc1,  // [H,H]
    const float* __restrict__ bfc1,
    const float* __restrict__ Wfc2,  // [32,H]
    const float* __restrict__ bfc2,
    float* __restrict__ out)         // [B,32]
{
    const int tid = threadIdx.x;
    const int w = tid >> 6;          // wave 0/1
    const int l = tid & 63;
    const int o = w * 32 + (l & 31); // owned output row
    const int kh = l >> 5;           // K-half: 0 -> j 0..31, 1 -> j 32..63
    const int b = blockIdx.x;

    __shared__ __align__(16) float xs[2][CH2 * HH];  // 2 x 8 KB double buffer
    __shared__ __align__(16) float hb1[HH];          // h1(t) exchange
    __shared__ __align__(16) float hb2[2][HH];       // h2 parity buffers
    __shared__ __align__(16) float zb[HH];           // FC z exchange

    // ---- weights: row o, K-half kh -> 48 f32x2 = 96 VGPRs ----
    f32x2 whh1v[16], wih2v[16], whh2v[16];
    LOADW2(whh1v, Whh1 + o * HH + kh * 32, 32);
    LOADW2(wih2v, Wih2 + o * HH + kh * 32, 32);
    LOADW2(whh2v, Whh2 + o * HH + kh * 32, 32);
    const float b2 = bih2[o] + bhh2[o];

    if (tid < HH) hb2[0][tid] = 0.f;  // h2(-1) = 0

    const float* xwb = xw + (size_t)b * TSTEPS * HH;

    // stage chunk 0 (each wave stages 4 KB linearly)
#pragma unroll
    for (int k = 0; k < 4; ++k) {
        const int off = (w * 4 + k) * 256;
        __builtin_amdgcn_global_load_lds(
            (const __attribute__((address_space(1))) void*)(xwb + off + l * 4),
            (__attribute__((address_space(3))) void*)(&xs[0][0] + off),
            16, 0, 0);
    }
    asm volatile("s_waitcnt vmcnt(0)" ::: "memory");
    __syncthreads();  // staging + hb2 zero visible

    f32x2 h1v[16];  // h1(t-1)[kh*32 .. +31] kept in registers across steps
#pragma unroll
    for (int k = 0; k < 16; ++k) h1v[k] = f32x2{0.f, 0.f};

// One step at compile-time parity P.
// C-round (Whh2@h2prev, LDS) + A-round (Whh1@h1prev, REGISTERS, no DS) overlap.
#define STEP(P, TT)                                                           \
    {                                                                         \
        const float xwv = cur[(TT) * HH + o]; /* 2-addr multicast read */     \
        f32x2 q0 = {0.f, 0.f}, q1 = {0.f, 0.f};  /* C partials */             \
        f32x2 r0 = {0.f, 0.f}, r1 = {0.f, 0.f};  /* A partials */             \
        _Pragma("unroll") for (int k = 0; k < 8; ++k) {                       \
            f32x4 hq = *(const f32x4*)(&hb2[P][kh * 32 + 4 * k]);             \
            q0 = __builtin_elementwise_fma(hq.lo, whh2v[2 * k], q0);          \
            q1 = __builtin_elementwise_fma(hq.hi, whh2v[2 * k + 1], q1);      \
            r0 = __builtin_elementwise_fma(h1v[2 * k], whh1v[2 * k], r0);     \
            r1 = __builtin_elementwise_fma(h1v[2 * k + 1], whh1v[2 * k + 1], r1);\
        }                                                                     \
        const float y2c_h = (q0.x + q0.y) + (q1.x + q1.y);                    \
        float y1_h = (r0.x + r0.y) + (r1.x + r1.y);                           \
        const float y1 = y1_h + __shfl_xor(y1_h, 32);                         \
        const float h1 = fast_tanh(xwv + y1);                                 \
        if (l < 32) hb1[o] = h1;                                              \
        __syncthreads(); /* barrier 1: h1 visible */                          \
        f32x2 s0 = {0.f, 0.f}, s1 = {0.f, 0.f};  /* B partials */             \
        _Pragma("unroll") for (int k = 0; k < 8; ++k) {                       \
            f32x4 hq = *(const f32x4*)(&hb1[kh * 32 + 4 * k]);                \
            h1v[2 * k] = hq.lo;       /* keep for next step's A-round */      \
            h1v[2 * k + 1] = hq.hi;                                           \
            s0 = __builtin_elementwise_fma(hq.lo, wih2v[2 * k], s0);          \
            s1 = __builtin_elementwise_fma(hq.hi, wih2v[2 * k + 1], s1);      \
        }                                                                     \
        float y2_h = (s0.x + s0.y) + (s1.x + s1.y) + y2c_h;                   \
        const float y2 = y2_h + __shfl_xor(y2_h, 32);                         \
        const float h2 = fast_tanh(b2 + y2);                                  \
        if (l < 32) hb2[(P) ^ 1][o] = h2;                                     \
        __syncthreads(); /* barrier 2: h2 visible; hb1 reusable */            \
    }

#pragma unroll 1
    for (int c = 0; c < NCH2; ++c) {
        const float* cur = &xs[c & 1][0];
        float* nxt = &xs[(c & 1) ^ 1][0];
        if (c + 1 < NCH2) {
#pragma unroll
            for (int k = 0; k < 4; ++k) {
                const int off = (w * 4 + k) * 256;
                __builtin_amdgcn_global_load_lds(
                    (const __attribute__((address_space(1))) void*)(
                        xwb + (c + 1) * CH2 * HH + off + l * 4),
                    (__attribute__((address_space(3))) void*)(nxt + off),
                    16, 0, 0);
            }
        }
#pragma unroll 1
        for (int tt = 0; tt < CH2; tt += 2) {
            STEP(0, tt)
            STEP(1, tt + 1)
        }
        // all waves must have completed staging before anyone reads next chunk
        asm volatile("s_waitcnt vmcnt(0)" ::: "memory");
        __syncthreads();
    }

    // ---- FC head; h2 final = hb2[0] (512 steps -> last write parity 1^1=0) ----
    {
        f32x2 wf[16];
        LOADW2(wf, Wfc1 + o * HH + kh * 32, 32);
        f32x2 u0 = {0.f, 0.f}, u1 = {0.f, 0.f};
#pragma unroll
        for (int k = 0; k < 8; ++k) {
            f32x4 hq = *(const f32x4*)(&hb2[0][kh * 32 + 4 * k]);
            u0 = __builtin_elementwise_fma(hq.lo, wf[2 * k], u0);
            u1 = __builtin_elementwise_fma(hq.hi, wf[2 * k + 1], u1);
        }
        float zh = (u0.x + u0.y) + (u1.x + u1.y);
        const float z = fmaxf(bfc1[o] + zh + __shfl_xor(zh, 32), 0.f);
        if (l < 32) zb[o] = z;
        __syncthreads();
    }
    {
        const int ow = w * 16 + (l & 15);  // 32 outputs across 2 waves
        const int kq = l >> 4;             // K-quarter (16 floats)
        f32x2 wg[8];
        LOADW2(wg, Wfc2 + ow * HH + kq * 16, 16);
        f32x2 u0 = {0.f, 0.f}, u1 = {0.f, 0.f};
#pragma unroll
        for (int k = 0; k < 4; ++k) {
            f32x4 zq = *(const f32x4*)(&zb[kq * 16 + 4 * k]);
            u0 = __builtin_elementwise_fma(zq.lo, wg[2 * k], u0);
            u1 = __builtin_elementwise_fma(zq.hi, wg[2 * k + 1], u1);
        }
        float v = (u0.x + u0.y) + (u1.x + u1.y);
        v += __shfl_xor(v, 16);
        v += __shfl_xor(v, 32);
        if (l < 16) out[b * 32 + ow] = bfc2[ow] + v;
    }
}

// ---------------- Fallback (fused, used only if ws too small) ----
__device__ __forceinline__ void stage8k_fb(const float* g, float* l, int lane) {
#pragma unroll
    for (int k = 0; k < 8; ++k) {
        __builtin_amdgcn_global_load_lds(
            (const __attribute__((address_space(1))) void*)(g + k * 256 + lane * 4),
            (__attribute__((address_space(3))) void*)(l + k * 256),
            16, 0, 0);
    }
}

__global__ void __launch_bounds__(256, 1) rnn_fused_fb(
    const float* __restrict__ x, const float* __restrict__ Wih1,
    const float* __restrict__ Whh1, const float* __restrict__ bih1,
    const float* __restrict__ bhh1, const float* __restrict__ Wih2,
    const float* __restrict__ Whh2, const float* __restrict__ bih2,
    const float* __restrict__ bhh2, const float* __restrict__ Wfc1,
    const float* __restrict__ bfc1, const float* __restrict__ Wfc2,
    const float* __restrict__ bfc2, float* __restrict__ out)
{
    const int wave = threadIdx.x >> 6;
    const int o = threadIdx.x & 63;
    const int b = blockIdx.x * 4 + wave;

    __shared__ __align__(16) float xs[4][2][64 * II];
    __shared__ __align__(16) float hb1[4][HH];
    __shared__ __align__(16) float hb2[4][HH];

    f32x2 wih1[II / 2], whh1[HH / 2], wih2[HH / 2], whh2[HH / 2];
    LOADW2(wih1, Wih1 + o * II, II);
    LOADW2(whh1, Whh1 + o * HH, HH);
    LOADW2(wih2, Wih2 + o * HH, HH);
    LOADW2(whh2, Whh2 + o * HH, HH);
    const float b1 = bih1[o] + bhh1[o];
    const float b2 = bih2[o] + bhh2[o];
    hb2[wave][o] = 0.f;

    const float* xb = x + (size_t)b * TSTEPS * II;
    float* l0 = &xs[wave][0][0];
    float* l1 = &xs[wave][1][0];
    stage8k_fb(xb, l0, o);
    asm volatile("s_waitcnt vmcnt(0)" ::: "memory");

    float acc1p = b1;
    float h2v = 0.f;
#pragma unroll 1
    for (int c = 0; c < TSTEPS / 64; ++c) {
        const float* cur = (c & 1) ? l1 : l0;
        float* nxt = (c & 1) ? l0 : l1;
        if (c + 1 < TSTEPS / 64) stage8k_fb(xb + (c + 1) * 64 * II, nxt, o);
#pragma unroll 1
        for (int tt = 0; tt < 64; ++tt) {
            const float* xr = cur + tt * II;
            f32x2 a0 = {acc1p, 0.f}, a1 = {0.f, 0.f};
#pragma unroll
            for (int k = 0; k < II / 4; ++k) {
                f32x4 xq = *(const f32x4*)(xr + 4 * k);
                a0 = __builtin_elementwise_fma(xq.lo, wih1[2 * k], a0);
                a1 = __builtin_elementwise_fma(xq.hi, wih1[2 * k + 1], a1);
            }
            float h1 = fast_tanh((a0.x + a1.x) + (a0.y + a1.y));
            hb1[wave][o] = h1;
            f32x2 q0 = {b2, 0.f}, q1 = {0.f, 0.f};
#pragma unroll
            for (int k = 0; k < HH / 4; ++k) {
                f32x4 hq = *(const f32x4*)(&hb2[wave][4 * k]);
                q0 = __builtin_elementwise_fma(hq.lo, whh2[2 * k], q0);
                q1 = __builtin_elementwise_fma(hq.hi, whh2[2 * k + 1], q1);
            }
            float acc2 = (q0.x + q1.x) + (q0.y + q1.y);
            f32x2 c0 = {acc2, 0.f}, c1 = {0.f, 0.f};
            f32x2 p0 = {b1, 0.f}, p1 = {0.f, 0.f};
#pragma unroll
            for (int k = 0; k < HH / 4; ++k) {
                f32x4 hq = *(const f32x4*)(&hb1[wave][4 * k]);
                c0 = __builtin_elementwise_fma(hq.lo, wih2[2 * k], c0);
                c1 = __builtin_elementwise_fma(hq.hi, wih2[2 * k + 1], c1);
                p0 = __builtin_elementwise_fma(hq.lo, whh1[2 * k], p0);
                p1 = __builtin_elementwise_fma(hq.hi, whh1[2 * k + 1], p1);
            }
            acc1p = (p0.x + p1.x) + (p0.y + p1.y);
            h2v = fast_tanh((c0.x + c1.x) + (c0.y + c1.y));
            hb2[wave][o] = h2v;
        }
        asm volatile("s_waitcnt vmcnt(0)" ::: "memory");
    }

    f32x2 wf[HH / 2];
    LOADW2(wf, Wfc1 + o * HH, HH);
    f32x2 z0 = {bfc1[o], 0.f}, z1 = {0.f, 0.f};
#pragma unroll
    for (int k = 0; k < HH / 4; ++k) {
        f32x4 hq = *(const f32x4*)(&hb2[wave][4 * k]);
        z0 = __builtin_elementwise_fma(hq.lo, wf[2 * k], z0);
        z1 = __builtin_elementwise_fma(hq.hi, wf[2 * k + 1], z1);
    }
    float z = fmaxf((z0.x + z1.x) + (z0.y + z1.y), 0.f);
    hb1[wave][o] = z;
    const int oo = o & 31;
    LOADW2(wf, Wfc2 + oo * HH, HH);
    f32x2 y0 = {bfc2[oo], 0.f}, y1 = {0.f, 0.f};
#pragma unroll
    for (int k = 0; k < HH / 4; ++k) {
        f32x4 zq = *(const f32x4*)(&hb1[wave][4 * k]);
        y0 = __builtin_elementwise_fma(zq.lo, wf[2 * k], y0);
        y1 = __builtin_elementwise_fma(zq.hi, wf[2 * k + 1], y1);
    }
    if (o < 32) out[b * 32 + oo] = (y0.x + y1.x) + (y0.y + y1.y);
}

extern "C" void kernel_launch(void* const* d_in, const int* in_sizes, int n_in,
                              void* d_out, int out_size, void* d_ws, size_t ws_size,
                              hipStream_t stream) {
    const float* x    = (const float*)d_in[0];
    const float* Wih1 = (const float*)d_in[1];
    const float* Whh1 = (const float*)d_in[2];
    const float* bih1 = (const float*)d_in[3];
    const float* bhh1 = (const float*)d_in[4];
    const float* Wih2 = (const float*)d_in[5];
    const float* Whh2 = (const float*)d_in[6];
    const float* bih2 = (const float*)d_in[7];
    const float* bhh2 = (const float*)d_in[8];
    const float* Wfc1 = (const float*)d_in[9];
    const float* bfc1 = (const float*)d_in[10];
    const float* Wfc2 = (const float*)d_in[11];
    const float* bfc2 = (const float*)d_in[12];
    float* out = (float*)d_out;

    if (ws_size >= XWBYTES) {
        float* xw = (float*)d_ws;
        hipLaunchKernelGGL(xw_precompute, dim3(BATCH * TSTEPS / 64), dim3(256),
                           0, stream, x, Wih1, bih1, bhh1, xw);
        hipLaunchKernelGGL(rnn_rec, dim3(BATCH), dim3(128), 0, stream,
                           xw, Whh1, Wih2, Whh2, bih2, bhh2,
                           Wfc1, bfc1, Wfc2, bfc2, out);
    } else {
        hipLaunchKernelGGL(rnn_fused_fb, dim3(BATCH / 4), dim3(256), 0, stream,
                           x, Wih1, Whh1, bih1, bhh1, Wih2, Whh2, bih2, bhh2,
                           Wfc1, bfc1, Wfc2, bfc2, out);
    }
}